// Round 3
// baseline (29618.695 us; speedup 1.0000x reference)
//
#include <hip/hip_runtime.h>
#include <cstdint>
#include <cstddef>

// LSTM autoregressive decoder, BATCH=32, T=256, VOCAB=8192, HIDDEN=1024.
// Per step: kA (h@[Wp|Wh] partials, LDS h-broadcast, 4 cols/thread) ->
//           kB1 (logits + gumbel + argmax partials + z-reduce) ->
//           kB2 (argmax finalize + one-hot + LSTM cell).
// jax threefry (partitionable variant) reproduced bit-exactly.

namespace {

constexpr int BB = 32;       // batch
constexpr int TT = 256;      // time steps
constexpr int VV = 8192;     // vocab
constexpr int HH = 1024;     // hidden
constexpr int ZC = 4096;     // 4*H
constexpr int NCOL = VV + ZC;   // 12288 columns (logits | z)
constexpr int K0S = 8;       // u-split for K0 (9216/1152)

__host__ __device__ inline uint32_t rotl(uint32_t v, int r) {
  return (v << r) | (v >> (32 - r));
}

// Exact jax threefry2x32 (20 rounds).
__host__ __device__ inline void tf2x32(uint32_t k0, uint32_t k1,
                                       uint32_t x0, uint32_t x1,
                                       uint32_t &o0, uint32_t &o1) {
  const uint32_t ks2 = k0 ^ k1 ^ 0x1BD11BDAu;
  x0 += k0; x1 += k1;
#define R4A { x0+=x1; x1=rotl(x1,13); x1^=x0; x0+=x1; x1=rotl(x1,15); x1^=x0; \
              x0+=x1; x1=rotl(x1,26); x1^=x0; x0+=x1; x1=rotl(x1, 6); x1^=x0; }
#define R4B { x0+=x1; x1=rotl(x1,17); x1^=x0; x0+=x1; x1=rotl(x1,29); x1^=x0; \
              x0+=x1; x1=rotl(x1,16); x1^=x0; x0+=x1; x1=rotl(x1,24); x1^=x0; }
  R4A; x0 += k1;  x1 += ks2 + 1u;
  R4B; x0 += ks2; x1 += k0 + 2u;
  R4A; x0 += k0;  x1 += k1 + 3u;
  R4B; x0 += k1;  x1 += ks2 + 4u;
  R4A; x0 += ks2; x1 += k0 + 5u;
#undef R4A
#undef R4B
  o0 = x0; o1 = x1;
}

__device__ inline float sigf(float x) { return 1.0f / (1.0f + expf(-x)); }

// ---------------------------------------------------------------------------
// K0: z0 partials = x0 @ Wi + h0 @ Wh  (K = VOCAB + HIDDEN = 9216, split x8)
__global__ __launch_bounds__(256) void k0_partial(
    const float* __restrict__ inputs,   // [B][T][V], use t=0
    const float* __restrict__ h0,       // [B][H]
    const float* __restrict__ Wi,       // [V][ZC]
    const float* __restrict__ Wh,       // [H][ZC]
    float* __restrict__ zpart0)         // [K0S][B][ZC]
{
  const int cb = blockIdx.x % (ZC / 64);
  const int s  = blockIdx.x / (ZC / 64);
  const int c  = threadIdx.x & 63;
  const int w  = threadIdx.x >> 6;
  const int col = cb * 64 + c;
  const int u0 = s * 1152 + w * 288;

  float acc[BB];
#pragma unroll
  for (int b = 0; b < BB; ++b) acc[b] = 0.0f;

  for (int ui = 0; ui < 288; ++ui) {
    const int u = u0 + ui;
    const float wv = (u < VV) ? Wi[(size_t)u * ZC + col]
                              : Wh[(size_t)(u - VV) * ZC + col];
#pragma unroll
    for (int b = 0; b < BB; ++b) {
      const float a = (u < VV) ? inputs[(size_t)b * TT * VV + u]
                               : h0[b * HH + (u - VV)];
      acc[b] = fmaf(a, wv, acc[b]);
    }
  }

  __shared__ float red[4][BB][64];   // 32 KiB
#pragma unroll
  for (int b = 0; b < BB; ++b) red[w][b][c] = acc[b];
  __syncthreads();
  for (int i = threadIdx.x; i < BB * 64; i += 256) {
    const int b = i >> 6, cc = i & 63;
    const float s4 = red[0][b][cc] + red[1][b][cc] + red[2][b][cc] + red[3][b][cc];
    zpart0[((size_t)s * BB + b) * ZC + cb * 64 + cc] = s4;
  }
}

// K0b: zfull0[b][j] = bh[j] + sum_s zpart0[s][b][j]
__global__ __launch_bounds__(256) void k0_reduce(
    const float* __restrict__ zpart0, const float* __restrict__ bh,
    float* __restrict__ zfull0)
{
  const int idx = blockIdx.x * 256 + threadIdx.x;  // B*ZC = 131072
  const int b = idx / ZC, j = idx % ZC;
  float s = bh[j];
#pragma unroll
  for (int k = 0; k < K0S; ++k) s += zpart0[((size_t)k * BB + b) * ZC + j];
  zfull0[idx] = s;
}

// kInit: cell for step 0 from zfull0 -> cbuf, hbuf. grid 128 x 256.
__global__ __launch_bounds__(256) void kInit(
    const float* __restrict__ zfull0, const float* __restrict__ c0,
    float* __restrict__ cbuf, float* __restrict__ hbuf)
{
  const int idx = blockIdx.x * 256 + threadIdx.x;   // B*H = 32768
  const int b = idx >> 10, u = idx & 1023;
  const float* z = zfull0 + (size_t)b * ZC;
  const float zi = z[u], zf = z[HH + u], zg = z[2 * HH + u], zo = z[3 * HH + u];
  const float cc = sigf(zf) * c0[idx] + sigf(zi) * tanhf(zg);
  cbuf[idx] = cc;
  hbuf[idx] = sigf(zo) * tanhf(cc);
}

// ---------------------------------------------------------------------------
// kA: part[s][b][col] partials for [h@Wp | h@Wh].
// Block: 256 cols (4/thread as float4), u-slice of 1024/SPL; 4 waves split u;
// h staged in LDS (broadcast reads), float4 LDS reduce, coalesced part write.
template <int SPL>
__global__ __launch_bounds__(256) void kA(
    const float* __restrict__ hbuf,     // [B][H]
    const float* __restrict__ Wp,       // [H][V]
    const float* __restrict__ Wh,       // [H][ZC]
    float* __restrict__ part)           // [SPL][B][NCOL]
{
  constexpr int UB = HH / SPL;          // u per block (128 @ SPL=8)
  constexpr int UW = UB / 4;            // u per wave  (32)
  constexpr int UC = UW / 8;            // 8-u chunks  (4)
  constexpr int NCB = NCOL / 256;       // 48 col-blocks

  const int cb   = blockIdx.x % NCB;
  const int s    = blockIdx.x / NCB;
  const int lane = threadIdx.x & 63;
  const int w    = threadIdx.x >> 6;
  const int colbase = cb * 256;

  const float* W; int ldw, wcol0;
  if (colbase < VV) { W = Wp; ldw = VV; wcol0 = colbase + lane * 4; }
  else              { W = Wh; ldw = ZC; wcol0 = colbase - VV + lane * 4; }

  __shared__ __align__(16) float hs[BB][UB];   // 16 KiB @ SPL=8
  __shared__ float4 red4[4][8][64];            // 32 KiB

  const int u0 = s * UB;
  for (int f = threadIdx.x * 4; f < BB * UB; f += 256 * 4) {
    const int b = f / UB, uu = f % UB;
    *(float4*)&hs[b][uu] = *(const float4*)&hbuf[b * HH + u0 + uu];
  }
  __syncthreads();

  float4 acc[BB];
#pragma unroll
  for (int b = 0; b < BB; ++b) acc[b] = make_float4(0.f, 0.f, 0.f, 0.f);

  const float* wp = W + (size_t)(u0 + w * UW) * ldw + wcol0;
#pragma unroll 1
  for (int uc = 0; uc < UC; ++uc) {
    float4 wv[8];
#pragma unroll
    for (int k = 0; k < 8; ++k)
      wv[k] = *(const float4*)&wp[(size_t)(uc * 8 + k) * ldw];
#pragma unroll
    for (int b = 0; b < BB; ++b) {
      const float4 h0 = *(const float4*)&hs[b][w * UW + uc * 8];
      const float4 h1 = *(const float4*)&hs[b][w * UW + uc * 8 + 4];
      float4 a = acc[b];
      const float hv[8] = {h0.x, h0.y, h0.z, h0.w, h1.x, h1.y, h1.z, h1.w};
#pragma unroll
      for (int k = 0; k < 8; ++k) {
        a.x = fmaf(wv[k].x, hv[k], a.x);
        a.y = fmaf(wv[k].y, hv[k], a.y);
        a.z = fmaf(wv[k].z, hv[k], a.z);
        a.w = fmaf(wv[k].w, hv[k], a.w);
      }
      acc[b] = a;
    }
  }

  // reduce 4 waves x 8 batches per round, 4 rounds; coalesced float4 stores
#pragma unroll 1
  for (int rb = 0; rb < 4; ++rb) {
    __syncthreads();
#pragma unroll
    for (int bl = 0; bl < 8; ++bl) red4[w][bl][lane] = acc[rb * 8 + bl];
    __syncthreads();
    for (int i = threadIdx.x; i < 8 * 64; i += 256) {
      const int bl = i >> 6, cc = i & 63;
      const float4 r0 = red4[0][bl][cc], r1 = red4[1][bl][cc];
      const float4 r2 = red4[2][bl][cc], r3 = red4[3][bl][cc];
      float4 o;
      o.x = (r0.x + r1.x) + (r2.x + r3.x);
      o.y = (r0.y + r1.y) + (r2.y + r3.y);
      o.z = (r0.z + r1.z) + (r2.z + r3.z);
      o.w = (r0.w + r1.w) + (r2.w + r3.w);
      const int b = rb * 8 + bl;
      *(float4*)&part[((size_t)s * BB + b) * NCOL + colbase + cc * 4] = o;
    }
  }
}

// ---------------------------------------------------------------------------
// kB1: grid = B*8 blocks (b, seg of 1536 cols), 256 thr.
// logits cols: sum partials + bp -> out, preds=0, gumbel, argmax partial.
// z cols: sum partials + bh -> written back into part[0][b][col] (zred).
__global__ __launch_bounds__(256) void kB1(
    float* __restrict__ part,           // [SPL][B][NCOL]; part[0] z gets zred
    const float* __restrict__ bp,       // [V]
    const float* __restrict__ bh,       // [ZC]
    float* __restrict__ logits_out,     // [B][T][V]
    float* __restrict__ preds_out,      // [B][T][V]
    float* __restrict__ argval, int* __restrict__ argidx,   // [B][8]
    uint32_t ck0, uint32_t ck1, int t, int spl)
{
  const int b   = blockIdx.x >> 3;
  const int seg = blockIdx.x & 7;
  const int tid = threadIdx.x;
  float* lg_row = logits_out + ((size_t)b * TT + t) * VV;
  float* pr_row = preds_out  + ((size_t)b * TT + t) * VV;

  float best = -3.4e38f; int besti = 0x7fffffff;
#pragma unroll 1
  for (int it = 0; it < 6; ++it) {
    const int col = seg * 1536 + it * 256 + tid;
    float sum = 0.0f;
    for (int s = 0; s < spl; ++s)
      sum += part[((size_t)s * BB + b) * NCOL + col];
    if (col < VV) {
      const float lg = sum + bp[col];
      lg_row[col] = lg;
      pr_row[col] = 0.0f;
      uint32_t r0, r1;
      tf2x32(ck0, ck1, 0u, (uint32_t)(b * VV + col), r0, r1);
      const uint32_t bits = r0 ^ r1;
      const float u0 = __uint_as_float((bits >> 9) | 0x3f800000u) - 1.0f;
      const float uu = (u0 == 0.0f) ? 1.17549435e-38f : u0;
      const float val = lg - logf(-logf(uu));
      if (val > best) { best = val; besti = col; }   // ascending col
    } else {
      part[((size_t)b) * NCOL + col] = sum + bh[col - VV];   // zred in part[0]
    }
  }
  // block argmax reduce (wave shfl + cross-wave LDS)
#pragma unroll
  for (int off = 32; off; off >>= 1) {
    const float vo = __shfl_down(best, off);
    const int   io = __shfl_down(besti, off);
    if (vo > best || (vo == best && io < besti)) { best = vo; besti = io; }
  }
  __shared__ float wv_[4];
  __shared__ int   wi_[4];
  const int wid = tid >> 6, lane = tid & 63;
  if (lane == 0) { wv_[wid] = best; wi_[wid] = besti; }
  __syncthreads();
  if (tid == 0) {
    float v2 = wv_[0]; int i2 = wi_[0];
#pragma unroll
    for (int k = 1; k < 4; ++k) {
      if (wv_[k] > v2 || (wv_[k] == v2 && wi_[k] < i2)) { v2 = wv_[k]; i2 = wi_[k]; }
    }
    argval[b * 8 + seg] = v2;
    argidx[b * 8 + seg] = i2;
  }
}

// ---------------------------------------------------------------------------
// kB2: grid = B blocks, 256 thr: finalize tok, preds one-hot, LSTM cell.
__global__ __launch_bounds__(256) void kB2(
    const float* __restrict__ part,     // part[0][b][VV+...] = zred (w/ bh)
    const float* __restrict__ Wi,       // [V][ZC]
    const float* __restrict__ argval, const int* __restrict__ argidx,  // [B][8]
    float* __restrict__ preds_out,      // [B][T][V]
    float* __restrict__ cbuf, float* __restrict__ hbuf,   // [B][H]
    int t, int do_cell)
{
  const int b = blockIdx.x;
  const int tid = threadIdx.x;
  __shared__ int stok;
  if (tid == 0) {
    float v = argval[b * 8]; int idx = argidx[b * 8];
#pragma unroll
    for (int k = 1; k < 8; ++k) {
      const float vo = argval[b * 8 + k];
      const int   io = argidx[b * 8 + k];
      if (vo > v || (vo == v && io < idx)) { v = vo; idx = io; }
    }
    stok = idx;
    preds_out[((size_t)b * TT + t) * VV + idx] = 1.0f;
  }
  __syncthreads();
  if (!do_cell) return;
  const int tok = stok;

  const float* zr = part + (size_t)b * NCOL + VV;
  const float* wr = Wi + (size_t)tok * ZC;
#pragma unroll 1
  for (int k = 0; k < 4; ++k) {
    const int u = k * 256 + tid;
    const float zi = zr[u]            + wr[u];
    const float zf = zr[HH + u]       + wr[HH + u];
    const float zg = zr[2 * HH + u]   + wr[2 * HH + u];
    const float zo = zr[3 * HH + u]   + wr[3 * HH + u];
    const float cp = cbuf[b * HH + u];
    const float cc = sigf(zf) * cp + sigf(zi) * tanhf(zg);
    cbuf[b * HH + u] = cc;
    hbuf[b * HH + u] = sigf(zo) * tanhf(cc);
  }
}

}  // namespace

extern "C" void kernel_launch(void* const* d_in, const int* in_sizes, int n_in,
                              void* d_out, int out_size, void* d_ws, size_t ws_size,
                              hipStream_t stream) {
  const float* inputs = (const float*)d_in[0];
  const float* Wi     = (const float*)d_in[1];
  const float* Wh     = (const float*)d_in[2];
  const float* bh     = (const float*)d_in[3];
  const float* Wp     = (const float*)d_in[4];
  const float* bp     = (const float*)d_in[5];
  const float* c0     = (const float*)d_in[6];
  const float* h0     = (const float*)d_in[7];

  float* out_logits = (float*)d_out;
  float* out_preds  = out_logits + (size_t)BB * TT * VV;

  // Choose split-K factor by available workspace.
  const size_t partB8 = (size_t)8 * BB * NCOL * sizeof(float);   // 12.58 MB
  const size_t partB4 = (size_t)4 * BB * NCOL * sizeof(float);   //  6.29 MB
  const size_t tailB  = ((size_t)BB * HH * 2 + BB * 8 * 2) * sizeof(float);
  const int spl = (ws_size >= partB8 + tailB + 1024) ? 8 : 4;
  const size_t partB = (spl == 8) ? partB8 : partB4;

  uint8_t* ws = (uint8_t*)d_ws;
  float* part   = (float*)ws;                 // [spl][B][NCOL]
  float* zpart0 = (float*)ws;                 // [K0S][B][ZC] = 4 MB (overlap)
  float* zfull0 = (float*)(ws + 5u * 1024 * 1024);  // 512 KB, inside part
  size_t off = partB;
  float* cbuf   = (float*)(ws + off); off += (size_t)BB * HH * sizeof(float);
  float* hbuf   = (float*)(ws + off); off += (size_t)BB * HH * sizeof(float);
  float* argval = (float*)(ws + off); off += (size_t)BB * 8 * sizeof(float);
  int*   argidx = (int*)  (ws + off); off += (size_t)BB * 8 * sizeof(int);

  // Host-side threefry key chain from jax.random.key(42) = (0, 42).
  uint32_t k0 = 0u, k1 = 42u;
  uint32_t ck[TT][2];
  for (int t = 0; t < TT; ++t) {
    uint32_t a, b2; tf2x32(k0, k1, 0u, 1u, a, b2);
    ck[t][0] = a; ck[t][1] = b2;
    uint32_t n0, n1; tf2x32(k0, k1, 0u, 0u, n0, n1);
    k0 = n0; k1 = n1;
  }

  k0_partial<<<(ZC / 64) * K0S, 256, 0, stream>>>(inputs, h0, Wi, Wh, zpart0);
  k0_reduce<<<BB * ZC / 256, 256, 0, stream>>>(zpart0, bh, zfull0);
  kInit<<<BB * HH / 256, 256, 0, stream>>>(zfull0, c0, cbuf, hbuf);

  for (int t = 0; t < TT; ++t) {
    if (spl == 8)
      kA<8><<<(NCOL / 256) * 8, 256, 0, stream>>>(hbuf, Wp, Wh, part);
    else
      kA<4><<<(NCOL / 256) * 4, 256, 0, stream>>>(hbuf, Wp, Wh, part);
    kB1<<<BB * 8, 256, 0, stream>>>(part, bp, bh, out_logits, out_preds,
                                    argval, argidx, ck[t][0], ck[t][1], t, spl);
    kB2<<<BB, 256, 0, stream>>>(part, Wi, argval, argidx, out_preds,
                                cbuf, hbuf, t, (t < TT - 1) ? 1 : 0);
  }
}